// Round 9
// baseline (312.241 us; speedup 1.0000x reference)
//
#include <hip/hip_runtime.h>
#include <math.h>

// Problem constants (match reference)
#define B_    256
#define T_    4096
#define N_    8        // n
#define TWON_ 16       // 2n
#define H_    64
#define P_    144      // 2n + 2n^2
#define WBLK  64                 // one wave per block
#define NBLKX (T_ / WBLK)        // 64 blocks along T
#define PSTRIDE 20               // LDS row stride in half2 units: 80 B rows, 16B-aligned

// denominators
#define INV_MAIN  (1.0f / (float)(B_ * TWON_ * T_))   // 1/16777216
#define INV_SUP   (1.0f / (float)(B_ * (P_ + TWON_))) // 1/40960

#define TWO_LOG2E 2.8853900817779268f   // 2*log2(e): e^{2x} = 2^{x*TWO_LOG2E}

typedef __fp16   half2_t __attribute__((ext_vector_type(2)));  // cvt_pkrtz result type
typedef _Float16 half8_t __attribute__((ext_vector_type(8)));  // MFMA operand type
typedef float    f32x4   __attribute__((ext_vector_type(4)));

union HPack { half2_t h2[4]; half8_t h8; };   // MFMA operand pun
union RPack { uint4 u4[4]; half2_t h2[16]; }; // LDS row read pun (64 B)

__device__ __forceinline__ float wave_reduce(float v) {
    #pragma unroll
    for (int off = 32; off > 0; off >>= 1) v += __shfl_down(v, off, 64);
    return v;
}

// grid: (NBLKX, B_), block = 64 (one wave). Wave computes its 64 points via
// 4 MFMA tiles of 16 points; lat/dlat round-trip LDS packed half2 (5.1 KB).
// ONE chunk per wave: weight-setup registers (zw/zb, 32 regs) die before the
// epilogue — 2-chunk variant kept them live across it and spilled 96 MB to
// scratch (r8 regression). Single kernel: block partial -> atomicAdd(d_out);
// d_out poison 0xAAAAAAAA == -3.03e-13f is negligible -> no memset needed.
__global__ __launch_bounds__(WBLK, 6)
void pinn_main_kernel(const float* __restrict__ t_in,
                      const float* __restrict__ x_target,
                      const float* __restrict__ params_pred,
                      const float* __restrict__ params_target,
                      const float* __restrict__ ic_pred,
                      const float* __restrict__ ic_target,
                      const float* __restrict__ W1,
                      const float* __restrict__ b1,
                      const float* __restrict__ W2,
                      const float* __restrict__ b2,
                      float* __restrict__ out) {
    __shared__ __align__(16) half2_t spk[WBLK * PSTRIDE];  // 5.1 KB: (lat, dlat) packed

    const int lane = threadIdx.x;    // 0..63
    const int b    = blockIdx.y;
    const int q    = lane >> 4;      // quad
    const int mn   = lane & 15;      // A-row (point-in-tile) == B/C col n
    const int k0   = q * 8;          // this lane's k-group base (within K=32 half)

    const float* pp = params_pred + b * P_;   // uniform -> scalar loads
    const int tq = blockIdx.x * WBLK + lane;

    // ---- supervised loss (blocks with x==0; one per batch) ----
    float sup = 0.0f;
    if (blockIdx.x == 0) {
        #pragma unroll
        for (int i = lane; i < P_; i += WBLK) {   // 144 elems
            const float d = pp[i] - params_target[b * P_ + i];
            sup = fmaf(d, d, sup);
        }
        if (lane < TWON_) {
            const float d = ic_pred[b * TWON_ + lane] - ic_target[b * TWON_ + lane];
            sup = fmaf(d, d, sup);
        }
    }

    // ---- per-lane weight setup ----
    // E = e^{2x} = exp2(x*2log2e); tanh = 1 - 2/(E+1). exp2 limits give h=+-1, g=0.
    float zwlo[8], zblo[8], zwhi[8], zbhi[8];
    HPack Blo, Bhi, Plo, Phi;   // B[k][n]=W2[k][n]; B'[k][n]=W1[k]*W2[k][n]
    #pragma unroll
    for (int j2 = 0; j2 < 4; ++j2) {
        const int ka = k0 + 2 * j2, kb = ka + 1;
        const float w1a = W1[ka],      w1b = W1[kb];
        const float w1c = W1[32 + ka], w1d = W1[32 + kb];
        zwlo[2*j2] = TWO_LOG2E * w1a; zwlo[2*j2+1] = TWO_LOG2E * w1b;
        zwhi[2*j2] = TWO_LOG2E * w1c; zwhi[2*j2+1] = TWO_LOG2E * w1d;
        zblo[2*j2] = TWO_LOG2E * b1[ka];      zblo[2*j2+1] = TWO_LOG2E * b1[kb];
        zbhi[2*j2] = TWO_LOG2E * b1[32 + ka]; zbhi[2*j2+1] = TWO_LOG2E * b1[32 + kb];
        const float wa = W2[ka * TWON_ + mn],        wb = W2[kb * TWON_ + mn];
        const float wc = W2[(32 + ka) * TWON_ + mn], wd = W2[(32 + kb) * TWON_ + mn];
        Blo.h2[j2] = __builtin_amdgcn_cvt_pkrtz(wa, wb);
        Bhi.h2[j2] = __builtin_amdgcn_cvt_pkrtz(wc, wd);
        Plo.h2[j2] = __builtin_amdgcn_cvt_pkrtz(w1a * wa, w1b * wb);
        Phi.h2[j2] = __builtin_amdgcn_cvt_pkrtz(w1c * wc, w1d * wd);
    }
    const float b2n = b2[mn];

    // t for this wave's 64 points
    const float treg = t_in[b * T_ + tq];

    // ---- 4 tiles of 16 points each ----
    #pragma unroll
    for (int ti = 0; ti < 4; ++ti) {
        const float tt = __shfl(treg, ti * 16 + mn, 64);

        HPack Ah_lo, Ag_lo, Ah_hi, Ag_hi;
        #pragma unroll
        for (int j2 = 0; j2 < 4; ++j2) {
            // low half (k = k0+2j2, k0+2j2+1)
            float e0 = __builtin_amdgcn_exp2f(fmaf(tt, zwlo[2*j2],   zblo[2*j2]));
            float e1 = __builtin_amdgcn_exp2f(fmaf(tt, zwlo[2*j2+1], zblo[2*j2+1]));
            float r0 = __builtin_amdgcn_rcpf(e0 + 1.0f);
            float r1 = __builtin_amdgcn_rcpf(e1 + 1.0f);
            float h0 = fmaf(-2.0f, r0, 1.0f), h1 = fmaf(-2.0f, r1, 1.0f);
            float g0 = fmaf(-h0, h0, 1.0f),   g1 = fmaf(-h1, h1, 1.0f);
            Ah_lo.h2[j2] = __builtin_amdgcn_cvt_pkrtz(h0, h1);
            Ag_lo.h2[j2] = __builtin_amdgcn_cvt_pkrtz(g0, g1);
            // high half (k+32)
            e0 = __builtin_amdgcn_exp2f(fmaf(tt, zwhi[2*j2],   zbhi[2*j2]));
            e1 = __builtin_amdgcn_exp2f(fmaf(tt, zwhi[2*j2+1], zbhi[2*j2+1]));
            r0 = __builtin_amdgcn_rcpf(e0 + 1.0f);
            r1 = __builtin_amdgcn_rcpf(e1 + 1.0f);
            h0 = fmaf(-2.0f, r0, 1.0f); h1 = fmaf(-2.0f, r1, 1.0f);
            g0 = fmaf(-h0, h0, 1.0f);   g1 = fmaf(-h1, h1, 1.0f);
            Ah_hi.h2[j2] = __builtin_amdgcn_cvt_pkrtz(h0, h1);
            Ag_hi.h2[j2] = __builtin_amdgcn_cvt_pkrtz(g0, g1);
        }

        f32x4 lat = {b2n, b2n, b2n, b2n};
        lat = __builtin_amdgcn_mfma_f32_16x16x32_f16(Ah_lo.h8, Blo.h8, lat, 0, 0, 0);
        lat = __builtin_amdgcn_mfma_f32_16x16x32_f16(Ah_hi.h8, Bhi.h8, lat, 0, 0, 0);
        f32x4 dl = {0.0f, 0.0f, 0.0f, 0.0f};
        dl = __builtin_amdgcn_mfma_f32_16x16x32_f16(Ag_lo.h8, Plo.h8, dl, 0, 0, 0);
        dl = __builtin_amdgcn_mfma_f32_16x16x32_f16(Ag_hi.h8, Phi.h8, dl, 0, 0, 0);

        // C/D: col = lane&15 (=n), row = quad*4 + reg (= point-in-tile)
        const int rowbase = ti * 16 + 4 * q;
        #pragma unroll
        for (int r = 0; r < 4; ++r) {
            spk[(rowbase + r) * PSTRIDE + mn] = __builtin_amdgcn_cvt_pkrtz(lat[r], dl[r]);
        }
    }

    // ---- x_target loads: issued post-MFMA (VGPRs not live across MLP phase);
    // latency hidden by the LDS round-trip below ----
    const float* xt = x_target + (size_t)b * TWON_ * T_ + tq;
    float xtv[TWON_];
    #pragma unroll
    for (int k = 0; k < TWON_; ++k) xtv[k] = xt[(size_t)k * T_];

    __syncthreads();   // single-wave block: lgkmcnt drain + trivial barrier

    // ---- epilogue: one thread per point ----
    float lat[TWON_], dlat[TWON_];
    {
        RPack rp;
        const uint4* pr = (const uint4*)&spk[lane * PSTRIDE];  // 80-B rows: 16B aligned
        #pragma unroll
        for (int c = 0; c < 4; ++c) rp.u4[c] = pr[c];
        #pragma unroll
        for (int i = 0; i < TWON_; ++i) { lat[i] = (float)rp.h2[i].x; dlat[i] = (float)rp.h2[i].y; }
    }

    float a[N_], xs[N_], da_[N_], dxs[N_];
    #pragma unroll
    for (int i = 0; i < N_; ++i) { a[i] = lat[i]; da_[i] = dlat[i]; }
    #pragma unroll
    for (int i = 0; i < N_; ++i) {
        const float qm = lat[N_ + i] - pp[N_ + i];   // mu: scalar load
        xs[i]  = qm > 0.0f ? qm : 0.0f;
        dxs[i] = qm > 0.0f ? dlat[N_ + i] : 0.0f;
    }

    float acc = 0.0f;
    #pragma unroll
    for (int k = 0; k < N_; ++k) { const float d = a[k]  - xtv[k];      acc = fmaf(d, d, acc); }
    #pragma unroll
    for (int k = 0; k < N_; ++k) { const float d = xs[k] - xtv[N_ + k]; acc = fmaf(d, d, acc); }

    // physics: rhs_a = g + Pi@x - a ; rhs_x = (Gamma@a)*(mu - x). Pi/Gamma scalar loads.
    const float* Pi  = pp + 2 * N_;
    const float* Gam = pp + 2 * N_ + N_ * N_;
    #pragma unroll
    for (int i = 0; i < N_; ++i) {
        float s1 = pp[i] - a[i];   // g[i]
        #pragma unroll
        for (int j = 0; j < N_; ++j) s1 = fmaf(Pi[i * N_ + j], xs[j], s1);
        float d = da_[i] - s1;
        acc = fmaf(d, d, acc);

        float s2 = 0.0f;
        #pragma unroll
        for (int j = 0; j < N_; ++j) s2 = fmaf(Gam[i * N_ + j], a[j], s2);
        s2 *= (pp[N_ + i] - xs[i]);
        d = dxs[i] - s2;
        acc = fmaf(d, d, acc);
    }

    // scale + wave reduce -> one device-scope atomic per block
    float v = fmaf(acc, INV_MAIN, sup * INV_SUP);
    float w = wave_reduce(v);
    if (lane == 0) atomicAdd(out, w);
}

extern "C" void kernel_launch(void* const* d_in, const int* in_sizes, int n_in,
                              void* d_out, int out_size, void* d_ws, size_t ws_size,
                              hipStream_t stream) {
    const float* t_in          = (const float*)d_in[0];
    const float* x_target      = (const float*)d_in[1];
    const float* params_pred   = (const float*)d_in[2];
    const float* params_target = (const float*)d_in[3];
    const float* ic_pred       = (const float*)d_in[4];
    const float* ic_target     = (const float*)d_in[5];
    const float* W1            = (const float*)d_in[6];
    const float* b1            = (const float*)d_in[7];
    const float* W2            = (const float*)d_in[8];
    const float* b2            = (const float*)d_in[9];
    float* out = (float*)d_out;

    dim3 grid(NBLKX, B_);
    pinn_main_kernel<<<grid, WBLK, 0, stream>>>(t_in, x_target, params_pred,
                                                params_target, ic_pred, ic_target,
                                                W1, b1, W2, b2, out);
}

// Round 10
// 221.626 us; speedup vs baseline: 1.4089x; 1.4089x over previous
//
#include <hip/hip_runtime.h>
#include <math.h>

// Problem constants (match reference)
#define B_    256
#define T_    4096
#define N_    8        // n
#define TWON_ 16       // 2n
#define H_    64
#define P_    144      // 2n + 2n^2
#define BLK   128                // 2 waves per block (beats the ~16 WG-slot/CU cap)
#define PTSPB 128                // points per block (each wave owns 64)
#define NBLKX (T_ / PTSPB)       // 32 blocks along T
#define NPART (NBLKX * B_ * 2)   // 16384 per-wave partials
#define PSTRIDE 20               // LDS row stride in half2 units: 80 B rows, 16B-aligned
#define FBLK  1024               // finalize block size

// denominators
#define INV_MAIN  (1.0f / (float)(B_ * TWON_ * T_))   // 1/16777216
#define INV_SUP   (1.0f / (float)(B_ * (P_ + TWON_))) // 1/40960

#define TWO_LOG2E 2.8853900817779268f   // 2*log2(e): e^{2x} = 2^{x*TWO_LOG2E}

typedef __fp16   half2_t __attribute__((ext_vector_type(2)));  // cvt_pkrtz result type
typedef _Float16 half8_t __attribute__((ext_vector_type(8)));  // MFMA operand type
typedef float    f32x4   __attribute__((ext_vector_type(4)));

union HPack { half2_t h2[4]; half8_t h8; };   // MFMA operand pun
union RPack { uint4 u4[4]; half2_t h2[16]; }; // LDS row read pun (64 B)

__device__ __forceinline__ float wave_reduce(float v) {
    #pragma unroll
    for (int off = 32; off > 0; off >>= 1) v += __shfl_down(v, off, 64);
    return v;
}

// grid: (NBLKX, B_), block = 128 (2 waves). Each wave independently computes
// its 64 points via 4 MFMA tiles of 16; lat/dlat round-trip its own LDS slice
// packed half2 (block total 10240 B -> 16 WGs x 2 = 32 waves/CU; the 1-wave
// version capped at ~16 waves/CU on the WG-slot limit, r9 occupancy 47%).
// Tail: per-wave partial -> d_ws (NO same-address atomics: r9's 16384-atomic
// convoy serialized at ~13 ns each = +190 us).
__global__ __launch_bounds__(BLK, 8)
void pinn_main_kernel(const float* __restrict__ t_in,
                      const float* __restrict__ x_target,
                      const float* __restrict__ params_pred,
                      const float* __restrict__ params_target,
                      const float* __restrict__ ic_pred,
                      const float* __restrict__ ic_target,
                      const float* __restrict__ W1,
                      const float* __restrict__ b1,
                      const float* __restrict__ W2,
                      const float* __restrict__ b2,
                      float* __restrict__ partials) {
    __shared__ __align__(16) half2_t spk[BLK * PSTRIDE];  // 10240 B: 2 wave slices

    const int tid  = threadIdx.x;    // 0..127
    const int lane = tid & 63;
    const int wv   = tid >> 6;       // wave id in block (0/1)
    const int b    = blockIdx.y;
    const int q    = lane >> 4;      // quad
    const int mn   = lane & 15;      // A-row (point-in-tile) == B/C col n
    const int k0   = q * 8;          // this lane's k-group base (within K=32 half)

    const float* pp = params_pred + b * P_;   // uniform -> scalar loads
    const int tq = blockIdx.x * PTSPB + wv * 64 + lane;   // this thread's point

    // ---- supervised loss (blocks with x==0; one per batch; both waves share) ----
    float sup = 0.0f;
    if (blockIdx.x == 0) {
        #pragma unroll
        for (int i = tid; i < P_; i += BLK) {   // 144 elems over 128 threads
            const float d = pp[i] - params_target[b * P_ + i];
            sup = fmaf(d, d, sup);
        }
        if (tid < TWON_) {
            const float d = ic_pred[b * TWON_ + tid] - ic_target[b * TWON_ + tid];
            sup = fmaf(d, d, sup);
        }
    }

    // ---- per-lane weight setup ----
    // E = e^{2x} = exp2(x*2log2e); tanh = 1 - 2/(E+1). exp2 limits give h=+-1, g=0.
    float zwlo[8], zblo[8], zwhi[8], zbhi[8];
    HPack Blo, Bhi, Plo, Phi;   // B[k][n]=W2[k][n]; B'[k][n]=W1[k]*W2[k][n]
    #pragma unroll
    for (int j2 = 0; j2 < 4; ++j2) {
        const int ka = k0 + 2 * j2, kb = ka + 1;
        const float w1a = W1[ka],      w1b = W1[kb];
        const float w1c = W1[32 + ka], w1d = W1[32 + kb];
        zwlo[2*j2] = TWO_LOG2E * w1a; zwlo[2*j2+1] = TWO_LOG2E * w1b;
        zwhi[2*j2] = TWO_LOG2E * w1c; zwhi[2*j2+1] = TWO_LOG2E * w1d;
        zblo[2*j2] = TWO_LOG2E * b1[ka];      zblo[2*j2+1] = TWO_LOG2E * b1[kb];
        zbhi[2*j2] = TWO_LOG2E * b1[32 + ka]; zbhi[2*j2+1] = TWO_LOG2E * b1[32 + kb];
        const float wa = W2[ka * TWON_ + mn],        wb = W2[kb * TWON_ + mn];
        const float wc = W2[(32 + ka) * TWON_ + mn], wd = W2[(32 + kb) * TWON_ + mn];
        Blo.h2[j2] = __builtin_amdgcn_cvt_pkrtz(wa, wb);
        Bhi.h2[j2] = __builtin_amdgcn_cvt_pkrtz(wc, wd);
        Plo.h2[j2] = __builtin_amdgcn_cvt_pkrtz(w1a * wa, w1b * wb);
        Phi.h2[j2] = __builtin_amdgcn_cvt_pkrtz(w1c * wc, w1d * wd);
    }
    const float b2n = b2[mn];

    // t for this wave's 64 points
    const float treg = t_in[b * T_ + tq];

    // ---- 4 tiles of 16 points each (per wave) ----
    half2_t* myspk = spk + wv * 64 * PSTRIDE;   // this wave's slice
    #pragma unroll
    for (int ti = 0; ti < 4; ++ti) {
        const float tt = __shfl(treg, ti * 16 + mn, 64);

        HPack Ah_lo, Ag_lo, Ah_hi, Ag_hi;
        #pragma unroll
        for (int j2 = 0; j2 < 4; ++j2) {
            // low half (k = k0+2j2, k0+2j2+1)
            float e0 = __builtin_amdgcn_exp2f(fmaf(tt, zwlo[2*j2],   zblo[2*j2]));
            float e1 = __builtin_amdgcn_exp2f(fmaf(tt, zwlo[2*j2+1], zblo[2*j2+1]));
            float r0 = __builtin_amdgcn_rcpf(e0 + 1.0f);
            float r1 = __builtin_amdgcn_rcpf(e1 + 1.0f);
            float h0 = fmaf(-2.0f, r0, 1.0f), h1 = fmaf(-2.0f, r1, 1.0f);
            float g0 = fmaf(-h0, h0, 1.0f),   g1 = fmaf(-h1, h1, 1.0f);
            Ah_lo.h2[j2] = __builtin_amdgcn_cvt_pkrtz(h0, h1);
            Ag_lo.h2[j2] = __builtin_amdgcn_cvt_pkrtz(g0, g1);
            // high half (k+32)
            e0 = __builtin_amdgcn_exp2f(fmaf(tt, zwhi[2*j2],   zbhi[2*j2]));
            e1 = __builtin_amdgcn_exp2f(fmaf(tt, zwhi[2*j2+1], zbhi[2*j2+1]));
            r0 = __builtin_amdgcn_rcpf(e0 + 1.0f);
            r1 = __builtin_amdgcn_rcpf(e1 + 1.0f);
            h0 = fmaf(-2.0f, r0, 1.0f); h1 = fmaf(-2.0f, r1, 1.0f);
            g0 = fmaf(-h0, h0, 1.0f);   g1 = fmaf(-h1, h1, 1.0f);
            Ah_hi.h2[j2] = __builtin_amdgcn_cvt_pkrtz(h0, h1);
            Ag_hi.h2[j2] = __builtin_amdgcn_cvt_pkrtz(g0, g1);
        }

        f32x4 lat = {b2n, b2n, b2n, b2n};
        lat = __builtin_amdgcn_mfma_f32_16x16x32_f16(Ah_lo.h8, Blo.h8, lat, 0, 0, 0);
        lat = __builtin_amdgcn_mfma_f32_16x16x32_f16(Ah_hi.h8, Bhi.h8, lat, 0, 0, 0);
        f32x4 dl = {0.0f, 0.0f, 0.0f, 0.0f};
        dl = __builtin_amdgcn_mfma_f32_16x16x32_f16(Ag_lo.h8, Plo.h8, dl, 0, 0, 0);
        dl = __builtin_amdgcn_mfma_f32_16x16x32_f16(Ag_hi.h8, Phi.h8, dl, 0, 0, 0);

        // C/D: col = lane&15 (=n), row = quad*4 + reg (= point-in-tile)
        const int rowbase = ti * 16 + 4 * q;
        #pragma unroll
        for (int r = 0; r < 4; ++r) {
            myspk[(rowbase + r) * PSTRIDE + mn] = __builtin_amdgcn_cvt_pkrtz(lat[r], dl[r]);
        }
    }

    // ---- x_target loads: issued post-MFMA (VGPRs not live across MLP phase);
    // latency hidden by the LDS round-trip below ----
    const float* xt = x_target + (size_t)b * TWON_ * T_ + tq;
    float xtv[TWON_];
    #pragma unroll
    for (int k = 0; k < TWON_; ++k) xtv[k] = xt[(size_t)k * T_];

    __syncthreads();   // 2-wave barrier (each wave only touches its own slice)

    // ---- epilogue: one thread per point ----
    float lat[TWON_], dlat[TWON_];
    {
        RPack rp;
        const uint4* pr = (const uint4*)&myspk[lane * PSTRIDE];  // 80-B rows: 16B aligned
        #pragma unroll
        for (int c = 0; c < 4; ++c) rp.u4[c] = pr[c];
        #pragma unroll
        for (int i = 0; i < TWON_; ++i) { lat[i] = (float)rp.h2[i].x; dlat[i] = (float)rp.h2[i].y; }
    }

    float a[N_], xs[N_], da_[N_], dxs[N_];
    #pragma unroll
    for (int i = 0; i < N_; ++i) { a[i] = lat[i]; da_[i] = dlat[i]; }
    #pragma unroll
    for (int i = 0; i < N_; ++i) {
        const float qm = lat[N_ + i] - pp[N_ + i];   // mu: scalar load
        xs[i]  = qm > 0.0f ? qm : 0.0f;
        dxs[i] = qm > 0.0f ? dlat[N_ + i] : 0.0f;
    }

    float acc = 0.0f;
    #pragma unroll
    for (int k = 0; k < N_; ++k) { const float d = a[k]  - xtv[k];      acc = fmaf(d, d, acc); }
    #pragma unroll
    for (int k = 0; k < N_; ++k) { const float d = xs[k] - xtv[N_ + k]; acc = fmaf(d, d, acc); }

    // physics: rhs_a = g + Pi@x - a ; rhs_x = (Gamma@a)*(mu - x). Pi/Gamma scalar loads.
    const float* Pi  = pp + 2 * N_;
    const float* Gam = pp + 2 * N_ + N_ * N_;
    #pragma unroll
    for (int i = 0; i < N_; ++i) {
        float s1 = pp[i] - a[i];   // g[i]
        #pragma unroll
        for (int j = 0; j < N_; ++j) s1 = fmaf(Pi[i * N_ + j], xs[j], s1);
        float d = da_[i] - s1;
        acc = fmaf(d, d, acc);

        float s2 = 0.0f;
        #pragma unroll
        for (int j = 0; j < N_; ++j) s2 = fmaf(Gam[i * N_ + j], a[j], s2);
        s2 *= (pp[N_ + i] - xs[i]);
        d = dxs[i] - s2;
        acc = fmaf(d, d, acc);
    }

    // scale + wave reduce -> one partial per WAVE (no atomics)
    float v = fmaf(acc, INV_MAIN, sup * INV_SUP);
    float w = wave_reduce(v);
    if (lane == 0)
        partials[(blockIdx.y * gridDim.x + blockIdx.x) * 2 + wv] = w;
}

// one block of 1024: reduce NPART pre-scaled partials -> scalar
__global__ __launch_bounds__(FBLK)
void pinn_finalize_kernel(const float* __restrict__ partials,
                          float* __restrict__ out) {
    __shared__ float swsum[FBLK / 64];
    const int tid = threadIdx.x;

    const float4* p4 = (const float4*)partials;   // NPART/4 = 4096 float4s
    float v = 0.0f;
    #pragma unroll
    for (int c = 0; c < 4; ++c) {
        const float4 v4 = p4[tid + c * FBLK];
        v += (v4.x + v4.y) + (v4.z + v4.w);
    }

    float w = wave_reduce(v);
    if ((tid & 63) == 0) swsum[tid >> 6] = w;
    __syncthreads();
    if (tid == 0) {
        float s = 0.0f;
        #pragma unroll
        for (int i = 0; i < FBLK / 64; ++i) s += swsum[i];
        out[0] = s;
    }
}

extern "C" void kernel_launch(void* const* d_in, const int* in_sizes, int n_in,
                              void* d_out, int out_size, void* d_ws, size_t ws_size,
                              hipStream_t stream) {
    const float* t_in          = (const float*)d_in[0];
    const float* x_target      = (const float*)d_in[1];
    const float* params_pred   = (const float*)d_in[2];
    const float* params_target = (const float*)d_in[3];
    const float* ic_pred       = (const float*)d_in[4];
    const float* ic_target     = (const float*)d_in[5];
    const float* W1            = (const float*)d_in[6];
    const float* b1            = (const float*)d_in[7];
    const float* W2            = (const float*)d_in[8];
    const float* b2            = (const float*)d_in[9];
    float* out = (float*)d_out;
    float* partials = (float*)d_ws;   // NPART floats = 64 KB

    dim3 grid(NBLKX, B_);
    pinn_main_kernel<<<grid, BLK, 0, stream>>>(t_in, x_target, params_pred,
                                               params_target, ic_pred, ic_target,
                                               W1, b1, W2, b2, partials);
    pinn_finalize_kernel<<<1, FBLK, 0, stream>>>(partials, out);
}

// Round 11
// 130.715 us; speedup vs baseline: 2.3887x; 1.6955x over previous
//
#include <hip/hip_runtime.h>
#include <math.h>

// Problem constants (match reference)
#define B_    256
#define T_    4096
#define N_    8        // n
#define TWON_ 16       // 2n
#define H_    64
#define P_    144      // 2n + 2n^2
#define BLK   128                // 2 waves per block (beats the ~16 WG-slot/CU cap)
#define PTSPB 128                // points per block (each wave owns 64)
#define NBLKX (T_ / PTSPB)       // 32 blocks along T
#define NPART (NBLKX * B_ * 2)   // 16384 per-wave partials
#define PSTRIDE 20               // LDS row stride in half2 units: 80 B rows, 16B-aligned
#define FBLK  1024               // finalize block size

// denominators
#define INV_MAIN  (1.0f / (float)(B_ * TWON_ * T_))   // 1/16777216
#define INV_SUP   (1.0f / (float)(B_ * (P_ + TWON_))) // 1/40960

#define TWO_LOG2E 2.8853900817779268f   // 2*log2(e): e^{2x} = 2^{x*TWO_LOG2E}

typedef __fp16   half2_t __attribute__((ext_vector_type(2)));  // cvt_pkrtz result type
typedef _Float16 half8_t __attribute__((ext_vector_type(8)));  // MFMA operand type
typedef float    f32x4   __attribute__((ext_vector_type(4)));

union HPack { half2_t h2[4]; half8_t h8; };   // MFMA operand pun
union RPack { uint4 u4[4]; half2_t h2[16]; }; // LDS row read pun (64 B)

__device__ __forceinline__ float wave_reduce(float v) {
    #pragma unroll
    for (int off = 32; off > 0; off >>= 1) v += __shfl_down(v, off, 64);
    return v;
}

// grid: (NBLKX, B_), block = 128 (2 waves). Each wave independently computes
// its 64 points via 4 MFMA tiles of 16; lat/dlat round-trip its own LDS slice
// packed half2 (block total 10240 B; 16 blocks x 2 waves = 32 waves/CU max).
// __launch_bounds__(128, 6): VGPR cap 85 — the (128,8) variant capped at 64,
// crushed the allocator to 32 VGPRs and spilled 221 MB to scratch (r10).
// Kernel naturally uses ~40 VGPRs -> HW still schedules up to 8 waves/EU.
// Tail: per-wave partial -> d_ws (NO same-address atomics: r9's 16384-atomic
// convoy serialized at ~13 ns each = +190 us).
__global__ __launch_bounds__(BLK, 6)
void pinn_main_kernel(const float* __restrict__ t_in,
                      const float* __restrict__ x_target,
                      const float* __restrict__ params_pred,
                      const float* __restrict__ params_target,
                      const float* __restrict__ ic_pred,
                      const float* __restrict__ ic_target,
                      const float* __restrict__ W1,
                      const float* __restrict__ b1,
                      const float* __restrict__ W2,
                      const float* __restrict__ b2,
                      float* __restrict__ partials) {
    __shared__ __align__(16) half2_t spk[BLK * PSTRIDE];  // 10240 B: 2 wave slices

    const int tid  = threadIdx.x;    // 0..127
    const int lane = tid & 63;
    const int wv   = tid >> 6;       // wave id in block (0/1)
    const int b    = blockIdx.y;
    const int q    = lane >> 4;      // quad
    const int mn   = lane & 15;      // A-row (point-in-tile) == B/C col n
    const int k0   = q * 8;          // this lane's k-group base (within K=32 half)

    const float* pp = params_pred + b * P_;   // uniform -> scalar loads
    const int tq = blockIdx.x * PTSPB + wv * 64 + lane;   // this thread's point

    // ---- supervised loss (blocks with x==0; one per batch; both waves share) ----
    float sup = 0.0f;
    if (blockIdx.x == 0) {
        #pragma unroll
        for (int i = tid; i < P_; i += BLK) {   // 144 elems over 128 threads
            const float d = pp[i] - params_target[b * P_ + i];
            sup = fmaf(d, d, sup);
        }
        if (tid < TWON_) {
            const float d = ic_pred[b * TWON_ + tid] - ic_target[b * TWON_ + tid];
            sup = fmaf(d, d, sup);
        }
    }

    // ---- per-lane weight setup ----
    // E = e^{2x} = exp2(x*2log2e); tanh = 1 - 2/(E+1). exp2 limits give h=+-1, g=0.
    float zwlo[8], zblo[8], zwhi[8], zbhi[8];
    HPack Blo, Bhi, Plo, Phi;   // B[k][n]=W2[k][n]; B'[k][n]=W1[k]*W2[k][n]
    #pragma unroll
    for (int j2 = 0; j2 < 4; ++j2) {
        const int ka = k0 + 2 * j2, kb = ka + 1;
        const float w1a = W1[ka],      w1b = W1[kb];
        const float w1c = W1[32 + ka], w1d = W1[32 + kb];
        zwlo[2*j2] = TWO_LOG2E * w1a; zwlo[2*j2+1] = TWO_LOG2E * w1b;
        zwhi[2*j2] = TWO_LOG2E * w1c; zwhi[2*j2+1] = TWO_LOG2E * w1d;
        zblo[2*j2] = TWO_LOG2E * b1[ka];      zblo[2*j2+1] = TWO_LOG2E * b1[kb];
        zbhi[2*j2] = TWO_LOG2E * b1[32 + ka]; zbhi[2*j2+1] = TWO_LOG2E * b1[32 + kb];
        const float wa = W2[ka * TWON_ + mn],        wb = W2[kb * TWON_ + mn];
        const float wc = W2[(32 + ka) * TWON_ + mn], wd = W2[(32 + kb) * TWON_ + mn];
        Blo.h2[j2] = __builtin_amdgcn_cvt_pkrtz(wa, wb);
        Bhi.h2[j2] = __builtin_amdgcn_cvt_pkrtz(wc, wd);
        Plo.h2[j2] = __builtin_amdgcn_cvt_pkrtz(w1a * wa, w1b * wb);
        Phi.h2[j2] = __builtin_amdgcn_cvt_pkrtz(w1c * wc, w1d * wd);
    }
    const float b2n = b2[mn];

    // t for this wave's 64 points
    const float treg = t_in[b * T_ + tq];

    // ---- 4 tiles of 16 points each (per wave) ----
    half2_t* myspk = spk + wv * 64 * PSTRIDE;   // this wave's slice
    #pragma unroll
    for (int ti = 0; ti < 4; ++ti) {
        const float tt = __shfl(treg, ti * 16 + mn, 64);

        HPack Ah_lo, Ag_lo, Ah_hi, Ag_hi;
        #pragma unroll
        for (int j2 = 0; j2 < 4; ++j2) {
            // low half (k = k0+2j2, k0+2j2+1)
            float e0 = __builtin_amdgcn_exp2f(fmaf(tt, zwlo[2*j2],   zblo[2*j2]));
            float e1 = __builtin_amdgcn_exp2f(fmaf(tt, zwlo[2*j2+1], zblo[2*j2+1]));
            float r0 = __builtin_amdgcn_rcpf(e0 + 1.0f);
            float r1 = __builtin_amdgcn_rcpf(e1 + 1.0f);
            float h0 = fmaf(-2.0f, r0, 1.0f), h1 = fmaf(-2.0f, r1, 1.0f);
            float g0 = fmaf(-h0, h0, 1.0f),   g1 = fmaf(-h1, h1, 1.0f);
            Ah_lo.h2[j2] = __builtin_amdgcn_cvt_pkrtz(h0, h1);
            Ag_lo.h2[j2] = __builtin_amdgcn_cvt_pkrtz(g0, g1);
            // high half (k+32)
            e0 = __builtin_amdgcn_exp2f(fmaf(tt, zwhi[2*j2],   zbhi[2*j2]));
            e1 = __builtin_amdgcn_exp2f(fmaf(tt, zwhi[2*j2+1], zbhi[2*j2+1]));
            r0 = __builtin_amdgcn_rcpf(e0 + 1.0f);
            r1 = __builtin_amdgcn_rcpf(e1 + 1.0f);
            h0 = fmaf(-2.0f, r0, 1.0f); h1 = fmaf(-2.0f, r1, 1.0f);
            g0 = fmaf(-h0, h0, 1.0f);   g1 = fmaf(-h1, h1, 1.0f);
            Ah_hi.h2[j2] = __builtin_amdgcn_cvt_pkrtz(h0, h1);
            Ag_hi.h2[j2] = __builtin_amdgcn_cvt_pkrtz(g0, g1);
        }

        f32x4 lat = {b2n, b2n, b2n, b2n};
        lat = __builtin_amdgcn_mfma_f32_16x16x32_f16(Ah_lo.h8, Blo.h8, lat, 0, 0, 0);
        lat = __builtin_amdgcn_mfma_f32_16x16x32_f16(Ah_hi.h8, Bhi.h8, lat, 0, 0, 0);
        f32x4 dl = {0.0f, 0.0f, 0.0f, 0.0f};
        dl = __builtin_amdgcn_mfma_f32_16x16x32_f16(Ag_lo.h8, Plo.h8, dl, 0, 0, 0);
        dl = __builtin_amdgcn_mfma_f32_16x16x32_f16(Ag_hi.h8, Phi.h8, dl, 0, 0, 0);

        // C/D: col = lane&15 (=n), row = quad*4 + reg (= point-in-tile)
        const int rowbase = ti * 16 + 4 * q;
        #pragma unroll
        for (int r = 0; r < 4; ++r) {
            myspk[(rowbase + r) * PSTRIDE + mn] = __builtin_amdgcn_cvt_pkrtz(lat[r], dl[r]);
        }
    }

    // ---- x_target loads: issued post-MFMA (VGPRs not live across MLP phase);
    // latency hidden by the LDS round-trip below ----
    const float* xt = x_target + (size_t)b * TWON_ * T_ + tq;
    float xtv[TWON_];
    #pragma unroll
    for (int k = 0; k < TWON_; ++k) xtv[k] = xt[(size_t)k * T_];

    __syncthreads();   // 2-wave barrier (each wave only touches its own slice)

    // ---- epilogue: one thread per point ----
    float lat[TWON_], dlat[TWON_];
    {
        RPack rp;
        const uint4* pr = (const uint4*)&myspk[lane * PSTRIDE];  // 80-B rows: 16B aligned
        #pragma unroll
        for (int c = 0; c < 4; ++c) rp.u4[c] = pr[c];
        #pragma unroll
        for (int i = 0; i < TWON_; ++i) { lat[i] = (float)rp.h2[i].x; dlat[i] = (float)rp.h2[i].y; }
    }

    float a[N_], xs[N_], da_[N_], dxs[N_];
    #pragma unroll
    for (int i = 0; i < N_; ++i) { a[i] = lat[i]; da_[i] = dlat[i]; }
    #pragma unroll
    for (int i = 0; i < N_; ++i) {
        const float qm = lat[N_ + i] - pp[N_ + i];   // mu: scalar load
        xs[i]  = qm > 0.0f ? qm : 0.0f;
        dxs[i] = qm > 0.0f ? dlat[N_ + i] : 0.0f;
    }

    float acc = 0.0f;
    #pragma unroll
    for (int k = 0; k < N_; ++k) { const float d = a[k]  - xtv[k];      acc = fmaf(d, d, acc); }
    #pragma unroll
    for (int k = 0; k < N_; ++k) { const float d = xs[k] - xtv[N_ + k]; acc = fmaf(d, d, acc); }

    // physics: rhs_a = g + Pi@x - a ; rhs_x = (Gamma@a)*(mu - x). Pi/Gamma scalar loads.
    const float* Pi  = pp + 2 * N_;
    const float* Gam = pp + 2 * N_ + N_ * N_;
    #pragma unroll
    for (int i = 0; i < N_; ++i) {
        float s1 = pp[i] - a[i];   // g[i]
        #pragma unroll
        for (int j = 0; j < N_; ++j) s1 = fmaf(Pi[i * N_ + j], xs[j], s1);
        float d = da_[i] - s1;
        acc = fmaf(d, d, acc);

        float s2 = 0.0f;
        #pragma unroll
        for (int j = 0; j < N_; ++j) s2 = fmaf(Gam[i * N_ + j], a[j], s2);
        s2 *= (pp[N_ + i] - xs[i]);
        d = dxs[i] - s2;
        acc = fmaf(d, d, acc);
    }

    // scale + wave reduce -> one partial per WAVE (no atomics)
    float v = fmaf(acc, INV_MAIN, sup * INV_SUP);
    float w = wave_reduce(v);
    if (lane == 0)
        partials[(blockIdx.y * gridDim.x + blockIdx.x) * 2 + wv] = w;
}

// one block of 1024: reduce NPART pre-scaled partials -> scalar
__global__ __launch_bounds__(FBLK)
void pinn_finalize_kernel(const float* __restrict__ partials,
                          float* __restrict__ out) {
    __shared__ float swsum[FBLK / 64];
    const int tid = threadIdx.x;

    const float4* p4 = (const float4*)partials;   // NPART/4 = 4096 float4s
    float v = 0.0f;
    #pragma unroll
    for (int c = 0; c < 4; ++c) {
        const float4 v4 = p4[tid + c * FBLK];
        v += (v4.x + v4.y) + (v4.z + v4.w);
    }

    float w = wave_reduce(v);
    if ((tid & 63) == 0) swsum[tid >> 6] = w;
    __syncthreads();
    if (tid == 0) {
        float s = 0.0f;
        #pragma unroll
        for (int i = 0; i < FBLK / 64; ++i) s += swsum[i];
        out[0] = s;
    }
}

extern "C" void kernel_launch(void* const* d_in, const int* in_sizes, int n_in,
                              void* d_out, int out_size, void* d_ws, size_t ws_size,
                              hipStream_t stream) {
    const float* t_in          = (const float*)d_in[0];
    const float* x_target      = (const float*)d_in[1];
    const float* params_pred   = (const float*)d_in[2];
    const float* params_target = (const float*)d_in[3];
    const float* ic_pred       = (const float*)d_in[4];
    const float* ic_target     = (const float*)d_in[5];
    const float* W1            = (const float*)d_in[6];
    const float* b1            = (const float*)d_in[7];
    const float* W2            = (const float*)d_in[8];
    const float* b2            = (const float*)d_in[9];
    float* out = (float*)d_out;
    float* partials = (float*)d_ws;   // NPART floats = 64 KB

    dim3 grid(NBLKX, B_);
    pinn_main_kernel<<<grid, BLK, 0, stream>>>(t_in, x_target, params_pred,
                                               params_target, ic_pred, ic_target,
                                               W1, b1, W2, b2, partials);
    pinn_finalize_kernel<<<1, FBLK, 0, stream>>>(partials, out);
}

// Round 12
// 127.739 us; speedup vs baseline: 2.4444x; 1.0233x over previous
//
#include <hip/hip_runtime.h>
#include <math.h>

// Problem constants (match reference)
#define B_    256
#define T_    4096
#define N_    8        // n
#define TWON_ 16       // 2n
#define H_    64
#define P_    144      // 2n + 2n^2
#define WBLK  64                 // one wave per block
#define NBLKX (T_ / WBLK)        // 64 blocks along T
#define NPART (NBLKX * B_)       // 16384 partials
#define PSTRIDE 20               // LDS row stride in half2 units: 80 B rows, 16B-aligned
#define FBLK  1024               // finalize block size

// denominators
#define INV_MAIN  (1.0f / (float)(B_ * TWON_ * T_))   // 1/16777216
#define INV_SUP   (1.0f / (float)(B_ * (P_ + TWON_))) // 1/40960

#define TWO_LOG2E 2.8853900817779268f   // 2*log2(e): e^{2x} = 2^{x*TWO_LOG2E}

// ---- Session conclusions baked in (r1-r11) ----
// * 1-wave blocks, lb(64,6): best measured total (128.2 us). 2-wave lb(128,6)
//   was neutral (130.7); lb(128,8) VGPR-capped to 64 -> 221 MB spills (r10);
//   2-chunk amortization kept setup regs live across epilogue -> spills (r8).
// * NEVER same-address atomicAdd from 16k blocks: ~13 ns each, serial convoy,
//   +190 us (r9). Partials in d_ws + tiny finalize is the right tail.
// * MFMA (f16 in, fp32 acc) for the two 64x16 matvecs; tanh via exp2+rcp;
//   lat/dlat round-trip LDS packed half2, 80-B rows (2-way banks = free).
// * Remaining total (~128 us) is harness-dominated: 268 MB ws poison fill
//   (~40 us @ 83% HBM peak), input restores, launch gaps. Main kernel ~22 us.

typedef __fp16   half2_t __attribute__((ext_vector_type(2)));  // cvt_pkrtz result type
typedef _Float16 half8_t __attribute__((ext_vector_type(8)));  // MFMA operand type
typedef float    f32x4   __attribute__((ext_vector_type(4)));

union HPack { half2_t h2[4]; half8_t h8; };   // MFMA operand pun
union RPack { uint4 u4[4]; half2_t h2[16]; }; // LDS row read pun (64 B)

__device__ __forceinline__ float wave_reduce(float v) {
    #pragma unroll
    for (int off = 32; off > 0; off >>= 1) v += __shfl_down(v, off, 64);
    return v;
}

__global__ __launch_bounds__(WBLK, 6)
void pinn_main_kernel(const float* __restrict__ t_in,
                      const float* __restrict__ x_target,
                      const float* __restrict__ params_pred,
                      const float* __restrict__ params_target,
                      const float* __restrict__ ic_pred,
                      const float* __restrict__ ic_target,
                      const float* __restrict__ W1,
                      const float* __restrict__ b1,
                      const float* __restrict__ W2,
                      const float* __restrict__ b2,
                      float* __restrict__ partials) {
    __shared__ __align__(16) half2_t spk[WBLK * PSTRIDE];  // 5.1 KB: (lat, dlat) packed

    const int lane = threadIdx.x;    // 0..63
    const int b    = blockIdx.y;
    const int q    = lane >> 4;      // quad
    const int mn   = lane & 15;      // A-row (point-in-tile) == B/C col n
    const int k0   = q * 8;          // this lane's k-group base (within K=32 half)

    const float* pp = params_pred + b * P_;   // uniform -> scalar loads
    const int tq = blockIdx.x * WBLK + lane;

    // ---- supervised loss (blocks with x==0; one per batch) ----
    float sup = 0.0f;
    if (blockIdx.x == 0) {
        #pragma unroll
        for (int i = lane; i < P_; i += WBLK) {   // 144 elems
            const float d = pp[i] - params_target[b * P_ + i];
            sup = fmaf(d, d, sup);
        }
        if (lane < TWON_) {
            const float d = ic_pred[b * TWON_ + lane] - ic_target[b * TWON_ + lane];
            sup = fmaf(d, d, sup);
        }
    }

    // ---- per-lane weight setup ----
    // E = e^{2x} = exp2(x*2log2e); tanh = 1 - 2/(E+1). exp2 limits give h=+-1, g=0.
    float zwlo[8], zblo[8], zwhi[8], zbhi[8];
    HPack Blo, Bhi, Plo, Phi;   // B[k][n]=W2[k][n]; B'[k][n]=W1[k]*W2[k][n]
    #pragma unroll
    for (int j2 = 0; j2 < 4; ++j2) {
        const int ka = k0 + 2 * j2, kb = ka + 1;
        const float w1a = W1[ka],      w1b = W1[kb];
        const float w1c = W1[32 + ka], w1d = W1[32 + kb];
        zwlo[2*j2] = TWO_LOG2E * w1a; zwlo[2*j2+1] = TWO_LOG2E * w1b;
        zwhi[2*j2] = TWO_LOG2E * w1c; zwhi[2*j2+1] = TWO_LOG2E * w1d;
        zblo[2*j2] = TWO_LOG2E * b1[ka];      zblo[2*j2+1] = TWO_LOG2E * b1[kb];
        zbhi[2*j2] = TWO_LOG2E * b1[32 + ka]; zbhi[2*j2+1] = TWO_LOG2E * b1[32 + kb];
        const float wa = W2[ka * TWON_ + mn],        wb = W2[kb * TWON_ + mn];
        const float wc = W2[(32 + ka) * TWON_ + mn], wd = W2[(32 + kb) * TWON_ + mn];
        Blo.h2[j2] = __builtin_amdgcn_cvt_pkrtz(wa, wb);
        Bhi.h2[j2] = __builtin_amdgcn_cvt_pkrtz(wc, wd);
        Plo.h2[j2] = __builtin_amdgcn_cvt_pkrtz(w1a * wa, w1b * wb);
        Phi.h2[j2] = __builtin_amdgcn_cvt_pkrtz(w1c * wc, w1d * wd);
    }
    const float b2n = b2[mn];

    // t for this wave's 64 points
    const float treg = t_in[b * T_ + tq];

    // ---- 4 tiles of 16 points each ----
    #pragma unroll
    for (int ti = 0; ti < 4; ++ti) {
        const float tt = __shfl(treg, ti * 16 + mn, 64);

        HPack Ah_lo, Ag_lo, Ah_hi, Ag_hi;
        #pragma unroll
        for (int j2 = 0; j2 < 4; ++j2) {
            // low half (k = k0+2j2, k0+2j2+1)
            float e0 = __builtin_amdgcn_exp2f(fmaf(tt, zwlo[2*j2],   zblo[2*j2]));
            float e1 = __builtin_amdgcn_exp2f(fmaf(tt, zwlo[2*j2+1], zblo[2*j2+1]));
            float r0 = __builtin_amdgcn_rcpf(e0 + 1.0f);
            float r1 = __builtin_amdgcn_rcpf(e1 + 1.0f);
            float h0 = fmaf(-2.0f, r0, 1.0f), h1 = fmaf(-2.0f, r1, 1.0f);
            float g0 = fmaf(-h0, h0, 1.0f),   g1 = fmaf(-h1, h1, 1.0f);
            Ah_lo.h2[j2] = __builtin_amdgcn_cvt_pkrtz(h0, h1);
            Ag_lo.h2[j2] = __builtin_amdgcn_cvt_pkrtz(g0, g1);
            // high half (k+32)
            e0 = __builtin_amdgcn_exp2f(fmaf(tt, zwhi[2*j2],   zbhi[2*j2]));
            e1 = __builtin_amdgcn_exp2f(fmaf(tt, zwhi[2*j2+1], zbhi[2*j2+1]));
            r0 = __builtin_amdgcn_rcpf(e0 + 1.0f);
            r1 = __builtin_amdgcn_rcpf(e1 + 1.0f);
            h0 = fmaf(-2.0f, r0, 1.0f); h1 = fmaf(-2.0f, r1, 1.0f);
            g0 = fmaf(-h0, h0, 1.0f);   g1 = fmaf(-h1, h1, 1.0f);
            Ah_hi.h2[j2] = __builtin_amdgcn_cvt_pkrtz(h0, h1);
            Ag_hi.h2[j2] = __builtin_amdgcn_cvt_pkrtz(g0, g1);
        }

        f32x4 lat = {b2n, b2n, b2n, b2n};
        lat = __builtin_amdgcn_mfma_f32_16x16x32_f16(Ah_lo.h8, Blo.h8, lat, 0, 0, 0);
        lat = __builtin_amdgcn_mfma_f32_16x16x32_f16(Ah_hi.h8, Bhi.h8, lat, 0, 0, 0);
        f32x4 dl = {0.0f, 0.0f, 0.0f, 0.0f};
        dl = __builtin_amdgcn_mfma_f32_16x16x32_f16(Ag_lo.h8, Plo.h8, dl, 0, 0, 0);
        dl = __builtin_amdgcn_mfma_f32_16x16x32_f16(Ag_hi.h8, Phi.h8, dl, 0, 0, 0);

        // C/D: col = lane&15 (=n), row = quad*4 + reg (= point-in-tile)
        const int rowbase = ti * 16 + 4 * q;
        #pragma unroll
        for (int r = 0; r < 4; ++r) {
            spk[(rowbase + r) * PSTRIDE + mn] = __builtin_amdgcn_cvt_pkrtz(lat[r], dl[r]);
        }
    }

    // ---- x_target loads: issued post-MFMA (VGPRs not live across MLP phase);
    // latency hidden by the LDS round-trip below ----
    const float* xt = x_target + (size_t)b * TWON_ * T_ + tq;
    float xtv[TWON_];
    #pragma unroll
    for (int k = 0; k < TWON_; ++k) xtv[k] = xt[(size_t)k * T_];

    __syncthreads();   // single-wave block: lgkmcnt drain + trivial barrier

    // ---- epilogue: one thread per point ----
    float lat[TWON_], dlat[TWON_];
    {
        RPack rp;
        const uint4* pr = (const uint4*)&spk[lane * PSTRIDE];  // 80-B rows: 16B aligned
        #pragma unroll
        for (int c = 0; c < 4; ++c) rp.u4[c] = pr[c];
        #pragma unroll
        for (int i = 0; i < TWON_; ++i) { lat[i] = (float)rp.h2[i].x; dlat[i] = (float)rp.h2[i].y; }
    }

    float a[N_], xs[N_], da_[N_], dxs[N_];
    #pragma unroll
    for (int i = 0; i < N_; ++i) { a[i] = lat[i]; da_[i] = dlat[i]; }
    #pragma unroll
    for (int i = 0; i < N_; ++i) {
        const float qm = lat[N_ + i] - pp[N_ + i];   // mu: scalar load
        xs[i]  = qm > 0.0f ? qm : 0.0f;
        dxs[i] = qm > 0.0f ? dlat[N_ + i] : 0.0f;
    }

    float acc = 0.0f;
    #pragma unroll
    for (int k = 0; k < N_; ++k) { const float d = a[k]  - xtv[k];      acc = fmaf(d, d, acc); }
    #pragma unroll
    for (int k = 0; k < N_; ++k) { const float d = xs[k] - xtv[N_ + k]; acc = fmaf(d, d, acc); }

    // physics: rhs_a = g + Pi@x - a ; rhs_x = (Gamma@a)*(mu - x). Pi/Gamma scalar loads.
    const float* Pi  = pp + 2 * N_;
    const float* Gam = pp + 2 * N_ + N_ * N_;
    #pragma unroll
    for (int i = 0; i < N_; ++i) {
        float s1 = pp[i] - a[i];   // g[i]
        #pragma unroll
        for (int j = 0; j < N_; ++j) s1 = fmaf(Pi[i * N_ + j], xs[j], s1);
        float d = da_[i] - s1;
        acc = fmaf(d, d, acc);

        float s2 = 0.0f;
        #pragma unroll
        for (int j = 0; j < N_; ++j) s2 = fmaf(Gam[i * N_ + j], a[j], s2);
        s2 *= (pp[N_ + i] - xs[i]);
        d = dxs[i] - s2;
        acc = fmaf(d, d, acc);
    }

    // scale + wave reduce -> one partial per block (no atomics)
    float v = fmaf(acc, INV_MAIN, sup * INV_SUP);
    float w = wave_reduce(v);
    if (lane == 0) partials[blockIdx.y * gridDim.x + blockIdx.x] = w;
}

// one block of 1024: reduce NPART pre-scaled partials -> scalar
__global__ __launch_bounds__(FBLK)
void pinn_finalize_kernel(const float* __restrict__ partials,
                          float* __restrict__ out) {
    __shared__ float swsum[FBLK / 64];
    const int tid = threadIdx.x;

    const float4* p4 = (const float4*)partials;   // NPART/4 = 4096 float4s
    float v = 0.0f;
    #pragma unroll
    for (int c = 0; c < 4; ++c) {
        const float4 v4 = p4[tid + c * FBLK];
        v += (v4.x + v4.y) + (v4.z + v4.w);
    }

    float w = wave_reduce(v);
    if ((tid & 63) == 0) swsum[tid >> 6] = w;
    __syncthreads();
    if (tid == 0) {
        float s = 0.0f;
        #pragma unroll
        for (int i = 0; i < FBLK / 64; ++i) s += swsum[i];
        out[0] = s;
    }
}

extern "C" void kernel_launch(void* const* d_in, const int* in_sizes, int n_in,
                              void* d_out, int out_size, void* d_ws, size_t ws_size,
                              hipStream_t stream) {
    const float* t_in          = (const float*)d_in[0];
    const float* x_target      = (const float*)d_in[1];
    const float* params_pred   = (const float*)d_in[2];
    const float* params_target = (const float*)d_in[3];
    const float* ic_pred       = (const float*)d_in[4];
    const float* ic_target     = (const float*)d_in[5];
    const float* W1            = (const float*)d_in[6];
    const float* b1            = (const float*)d_in[7];
    const float* W2            = (const float*)d_in[8];
    const float* b2            = (const float*)d_in[9];
    float* out = (float*)d_out;
    float* partials = (float*)d_ws;   // NPART floats = 64 KB

    dim3 grid(NBLKX, B_);
    pinn_main_kernel<<<grid, WBLK, 0, stream>>>(t_in, x_target, params_pred,
                                                params_target, ic_pred, ic_target,
                                                W1, b1, W2, b2, partials);
    pinn_finalize_kernel<<<1, FBLK, 0, stream>>>(partials, out);
}